// Round 1
// baseline (19349.692 us; speedup 1.0000x reference)
//
#include <hip/hip_runtime.h>
#include <hip/hip_bf16.h>

// Problem constants (from reference setup_inputs):
//   N=4096 nodes, T=64 tokens, V=30000 vocab, H=256 hidden, L=2 layers
#define NN 4096
#define TT 64
#define HH 256
#define GG 1024   // 4*H
#define NB 16     // nodes per block
#define NTHREADS 512

__device__ __forceinline__ float sig_(float x) {
    return 1.0f / (1.0f + __expf(-x));
}
__device__ __forceinline__ float tanh_(float x) {
    float e = __expf(-2.0f * x);
    return (1.0f - e) / (1.0f + e);
}

struct SmemT {
    float x[NB][HH];   // current layer input (embedding or lower-layer h)
    float h0[NB][HH];  // layer-0 hidden state
    float h1[NB][HH];  // layer-1 hidden state
};

// One LSTM layer step for this block's NB nodes.
// Thread owns hidden unit m (all four gates) for 8 nodes starting at n0.
// s_in: layer input [NB][H]; s_h: this layer's h (read old, write new).
__device__ __forceinline__ void lstm_layer(
    const float (&s_in)[NB][HH],
    float (&s_h)[NB][HH],
    const float* __restrict__ Wxl,   // [H][4H]
    const float* __restrict__ Whl,   // [H][4H]
    float bi, float bf, float bg, float bo,
    float* cc, int m, int n0)
{
    float ai[8], af[8], ag[8], ao[8];
#pragma unroll
    for (int n = 0; n < 8; ++n) { ai[n] = bi; af[n] = bf; ag[n] = bg; ao[n] = bo; }

    // x-part: z += x @ Wx
    const float* p = Wxl + m;
#pragma unroll 4
    for (int k = 0; k < HH; ++k) {
        float wi = p[0];
        float wf = p[HH];
        float wg = p[2 * HH];
        float wo = p[3 * HH];
        p += GG;
#pragma unroll
        for (int n = 0; n < 8; ++n) {
            float xv = s_in[n0 + n][k];   // wave-broadcast LDS read
            ai[n] = fmaf(xv, wi, ai[n]);
            af[n] = fmaf(xv, wf, af[n]);
            ag[n] = fmaf(xv, wg, ag[n]);
            ao[n] = fmaf(xv, wo, ao[n]);
        }
    }

    // h-part: z += h_prev @ Wh
    p = Whl + m;
#pragma unroll 4
    for (int k = 0; k < HH; ++k) {
        float wi = p[0];
        float wf = p[HH];
        float wg = p[2 * HH];
        float wo = p[3 * HH];
        p += GG;
#pragma unroll
        for (int n = 0; n < 8; ++n) {
            float hv = s_h[n0 + n][k];
            ai[n] = fmaf(hv, wi, ai[n]);
            af[n] = fmaf(hv, wf, af[n]);
            ag[n] = fmaf(hv, wg, ag[n]);
            ao[n] = fmaf(hv, wo, ao[n]);
        }
    }

    __syncthreads();  // everyone done reading old s_h (and s_in) before overwrite

#pragma unroll
    for (int n = 0; n < 8; ++n) {
        float iv = sig_(ai[n]);
        float fv = sig_(af[n]);
        float gv = tanh_(ag[n]);
        float ov = sig_(ao[n]);
        float c = fmaf(fv, cc[n], iv * gv);
        cc[n] = c;
        s_h[n0 + n][m] = ov * tanh_(c);
    }
    __syncthreads();  // new h visible to all
}

__global__ __launch_bounds__(NTHREADS, 2) void node_lstm_kernel(
    const int* __restrict__ data,     // [N, T] int32 token ids
    const float* __restrict__ embed,  // [V, H]
    const float* __restrict__ Wx,     // [2, H, 4H]
    const float* __restrict__ Wh,     // [2, H, 4H]
    const float* __restrict__ bias,   // [2, 4H]
    float* __restrict__ out,          // [N, H]
    int vocab)
{
    __shared__ SmemT sm;

    const int tid = threadIdx.x;
    const int m = tid & (HH - 1);       // hidden unit this thread owns
    const int n0 = (tid >> 8) << 3;     // node sub-range: 0..7 or 8..15
    const int nodeBase = blockIdx.x * NB;

    const float* Wx0 = Wx;
    const float* Wh0 = Wh;
    const float* Wx1 = Wx + HH * GG;
    const float* Wh1 = Wh + HH * GG;

    const float b0i = bias[m];
    const float b0f = bias[m + HH];
    const float b0g = bias[m + 2 * HH];
    const float b0o = bias[m + 3 * HH];
    const float b1i = bias[GG + m];
    const float b1f = bias[GG + m + HH];
    const float b1g = bias[GG + m + 2 * HH];
    const float b1o = bias[GG + m + 3 * HH];

    float c0[8], c1[8];
#pragma unroll
    for (int n = 0; n < 8; ++n) { c0[n] = 0.0f; c1[n] = 0.0f; }

    // zero initial hidden states
    for (int idx = tid; idx < NB * HH; idx += NTHREADS) {
        (&sm.h0[0][0])[idx] = 0.0f;
        (&sm.h1[0][0])[idx] = 0.0f;
    }
    __syncthreads();

    for (int t = 0; t < TT; ++t) {
        // stage token embeddings for this step: 16 rows x 256 floats
        for (int idx = tid; idx < NB * HH; idx += NTHREADS) {
            int n = idx >> 8;          // idx / HH
            int k = idx & (HH - 1);
            int row = data[(nodeBase + n) * TT + t];
            // defensive clamp (protects against dtype surprises; no-op normally)
            row = min(max(row, 0), vocab - 1);
            sm.x[n][k] = embed[row * HH + k];
        }
        __syncthreads();

        lstm_layer(sm.x, sm.h0, Wx0, Wh0, b0i, b0f, b0g, b0o, c0, m, n0);
        lstm_layer(sm.h0, sm.h1, Wx1, Wh1, b1i, b1f, b1g, b1o, c1, m, n0);
    }

    // final top-layer hidden state -> out
    for (int idx = tid; idx < NB * HH; idx += NTHREADS) {
        int n = idx >> 8;
        int k = idx & (HH - 1);
        out[(nodeBase + n) * HH + k] = sm.h1[n][k];
    }
}

extern "C" void kernel_launch(void* const* d_in, const int* in_sizes, int n_in,
                              void* d_out, int out_size, void* d_ws, size_t ws_size,
                              hipStream_t stream) {
    const int* data = (const int*)d_in[0];
    const float* embed = (const float*)d_in[1];
    const float* Wx = (const float*)d_in[2];
    const float* Wh = (const float*)d_in[3];
    const float* bias = (const float*)d_in[4];
    float* out = (float*)d_out;

    const int vocab = in_sizes[1] / HH;  // 30000

    dim3 grid(NN / NB);     // 256 blocks
    dim3 block(NTHREADS);   // 512 threads
    node_lstm_kernel<<<grid, block, 0, stream>>>(data, embed, Wx, Wh, bias, out, vocab);
}

// Round 2
// 1869.765 us; speedup vs baseline: 10.3487x; 10.3487x over previous
//
#include <hip/hip_runtime.h>
#include <hip/hip_bf16.h>

// Problem: N=4096 nodes, T=64, V=30000, H=256, L=2 layers, gates=4H=1024
#define NN 4096
#define TT 64
#define HH 256
#define GG 1024

typedef _Float16 f16;
typedef __attribute__((ext_vector_type(8))) _Float16 f16x8;
typedef __attribute__((ext_vector_type(4))) float f32x4;

// ---------------- workspace layout ----------------
// [0, EMB_BYTES)              : embed as fp16 [30000][256]
// [EMB_BYTES, +WP_BYTES)      : packed fp16 weights, MFMA-B-fragment order
//   Wp[l][kk][nt][lane][j] = Wcat_l[kk*32 + 8*(lane>>4) + j][nt*16 + (lane&15)]
//   where Wcat_l = concat_K(Wx[l] (k<256), Wh[l] (k>=256))  -> [512][1024]
#define EMB_ELEMS (30000 * HH)
#define EMB_BYTES ((size_t)EMB_ELEMS * 2)
#define WP_ELEMS (2 * 512 * GG)
#define WP_BYTES ((size_t)WP_ELEMS * 2)
#define WS_NEED (EMB_BYTES + WP_BYTES)

__device__ __forceinline__ float sig_(float x) {
    return 1.0f / (1.0f + __expf(-x));
}
__device__ __forceinline__ float tanh_(float x) {
    x = fminf(fmaxf(x, -15.0f), 15.0f);   // avoid inf/inf -> nan
    float e = __expf(-2.0f * x);
    return (1.0f - e) / (1.0f + e);
}

// ---------------- precompute kernels ----------------
__global__ void convert_embed(const float* __restrict__ e, f16* __restrict__ o, int n8) {
    int i = blockIdx.x * 256 + threadIdx.x;
    if (i >= n8) return;
    size_t p = (size_t)i * 8;
    float4 a = *(const float4*)(e + p);
    float4 b = *(const float4*)(e + p + 4);
    f16x8 v = { (f16)a.x, (f16)a.y, (f16)a.z, (f16)a.w,
                (f16)b.x, (f16)b.y, (f16)b.z, (f16)b.w };
    *(f16x8*)(o + p) = v;
}

__global__ void pack_weights(const float* __restrict__ Wx, const float* __restrict__ Wh,
                             f16* __restrict__ Wp) {
    int t = blockIdx.x * 256 + threadIdx.x;   // 131072 items, each packs 8 values
    int lane = t & 63;
    int nt = (t >> 6) & 63;
    int kk = (t >> 12) & 15;
    int l = t >> 16;
    int n = nt * 16 + (lane & 15);
    int kbase = kk * 32 + 8 * (lane >> 4);    // never straddles the 256 boundary
    const float* src = (kbase < 256) ? (Wx + (size_t)l * HH * GG + (size_t)kbase * GG + n)
                                     : (Wh + (size_t)l * HH * GG + (size_t)(kbase - 256) * GG + n);
    f16x8 v;
#pragma unroll
    for (int j = 0; j < 8; ++j) v[j] = (f16)src[(size_t)j * GG];
    *(f16x8*)(Wp + (size_t)t * 8) = v;
}

// ---------------- main recurrent kernel ----------------
#define NB 32
#define NTH 512
#define LD 264   // padded fp16 row stride (256 + 8) to break LDS bank alignment

// One layer step: acc = bias; acc += bx @ Wcat[:256] + bh @ Wcat[256:]; gates; bh <- new h.
__device__ __forceinline__ void layer_step(
    const f16 (*bx)[LD], f16 (*bh)[LD],
    const f16* __restrict__ wlayer,   // packed weights for this layer
    const float* breg_l, float* c_l,  // [8] bias regs, [16] c-state
    int lane, int w)
{
    f32x4 acc[2][8];
#pragma unroll
    for (int mt = 0; mt < 2; ++mt)
#pragma unroll
        for (int tt = 0; tt < 8; ++tt) {
            float b = breg_l[tt];
            acc[mt][tt] = (f32x4){b, b, b, b};
        }

    const int arow = lane & 15;
    const int koff = 8 * (lane >> 4);
    const f16* wl = wlayer + (size_t)lane * 8;

    // x-part (kk = 0..7 of packed K)
#pragma unroll 2
    for (int kk = 0; kk < 8; ++kk) {
        int k0 = kk * 32 + koff;
        f16x8 a0 = *(const f16x8*)&bx[arow][k0];
        f16x8 a1 = *(const f16x8*)&bx[arow + 16][k0];
        const f16* wkk = wl + (size_t)kk * 64 * 64 * 8;
#pragma unroll
        for (int tt = 0; tt < 8; ++tt) {
            int nt = (tt >> 1) * 16 + w * 2 + (tt & 1);
            f16x8 b = *(const f16x8*)(wkk + (size_t)nt * 64 * 8);
            acc[0][tt] = __builtin_amdgcn_mfma_f32_16x16x32_f16(a0, b, acc[0][tt], 0, 0, 0);
            acc[1][tt] = __builtin_amdgcn_mfma_f32_16x16x32_f16(a1, b, acc[1][tt], 0, 0, 0);
        }
    }
    // h-part (kk = 8..15 of packed K)
#pragma unroll 2
    for (int kk = 0; kk < 8; ++kk) {
        int k0 = kk * 32 + koff;
        f16x8 a0 = *(const f16x8*)&bh[arow][k0];
        f16x8 a1 = *(const f16x8*)&bh[arow + 16][k0];
        const f16* wkk = wl + (size_t)(kk + 8) * 64 * 64 * 8;
#pragma unroll
        for (int tt = 0; tt < 8; ++tt) {
            int nt = (tt >> 1) * 16 + w * 2 + (tt & 1);
            f16x8 b = *(const f16x8*)(wkk + (size_t)nt * 64 * 8);
            acc[0][tt] = __builtin_amdgcn_mfma_f32_16x16x32_f16(a0, b, acc[0][tt], 0, 0, 0);
            acc[1][tt] = __builtin_amdgcn_mfma_f32_16x16x32_f16(a1, b, acc[1][tt], 0, 0, 0);
        }
    }

    __syncthreads();  // all reads of old bh done before overwrite

    // gate math + h writeback.  C/D layout: col=lane&15, row=(lane>>4)*4+r (m89-verified)
#pragma unroll
    for (int mt = 0; mt < 2; ++mt)
#pragma unroll
        for (int sub = 0; sub < 2; ++sub) {
            f32x4 iv = acc[mt][0 + sub];
            f32x4 fv = acc[mt][2 + sub];
            f32x4 gv = acc[mt][4 + sub];
            f32x4 ov = acc[mt][6 + sub];
#pragma unroll
            for (int r = 0; r < 4; ++r) {
                float i_ = sig_(iv[r]);
                float f_ = sig_(fv[r]);
                float g_ = tanh_(gv[r]);
                float o_ = sig_(ov[r]);
                int ci = mt * 8 + sub * 4 + r;
                float c = fmaf(f_, c_l[ci], i_ * g_);
                c_l[ci] = c;
                float h = o_ * tanh_(c);
                int node = mt * 16 + (lane >> 4) * 4 + r;
                int unit = w * 32 + sub * 16 + (lane & 15);
                bh[node][unit] = (f16)h;
            }
        }
    __syncthreads();  // new h visible
}

__global__ __launch_bounds__(NTH, 2) void lstm_mfma(
    const int* __restrict__ data,
    const float* __restrict__ bias,
    const f16* __restrict__ emb,
    const f16* __restrict__ Wp,
    float* __restrict__ out,
    int vocab)
{
    __shared__ f16 x_lds[NB][LD];
    __shared__ f16 h0_lds[NB][LD];
    __shared__ f16 h1_lds[NB][LD];

    const int tid = threadIdx.x;
    const int lane = tid & 63;
    const int w = tid >> 6;
    const int n0 = blockIdx.x * NB;

    for (int i = tid; i < NB * LD; i += NTH) {
        (&h0_lds[0][0])[i] = (f16)0.0f;
        (&h1_lds[0][0])[i] = (f16)0.0f;
    }

    float breg[2][8];
#pragma unroll
    for (int l = 0; l < 2; ++l)
#pragma unroll
        for (int tt = 0; tt < 8; ++tt) {
            int col = (tt >> 1) * 256 + w * 32 + (tt & 1) * 16 + (lane & 15);
            breg[l][tt] = bias[l * GG + col];
        }

    float cst[2][16];
#pragma unroll
    for (int i = 0; i < 32; ++i) (&cst[0][0])[i] = 0.0f;

    __syncthreads();

    const f16* Wp0 = Wp;
    const f16* Wp1 = Wp + (size_t)16 * 64 * 64 * 8;

    for (int t = 0; t < TT; ++t) {
        // gather this step's embeddings: 32 rows x 256 fp16
        {
            int n = tid >> 4;
            int cg = (tid & 15) * 16;
            int row = data[(n0 + n) * TT + t];
            row = min(max(row, 0), vocab - 1);
            const f16* src = emb + (size_t)row * HH + cg;
            f16x8 v0 = *(const f16x8*)src;
            f16x8 v1 = *(const f16x8*)(src + 8);
            *(f16x8*)&x_lds[n][cg] = v0;
            *(f16x8*)&x_lds[n][cg + 8] = v1;
        }
        __syncthreads();

        layer_step(x_lds, h0_lds, Wp0, breg[0], cst[0], lane, w);
        layer_step((const f16(*)[LD])h0_lds, h1_lds, Wp1, breg[1], cst[1], lane, w);
    }

    for (int i = tid; i < NB * HH; i += NTH) {
        int n = i >> 8;
        int k = i & 255;
        out[(size_t)(n0 + n) * HH + k] = (float)h1_lds[n][k];
    }
}

// ---------------- fallback (round-1 fp32 kernel, used only if ws too small) ----------------
#define FNB 16
#define FNTH 512
struct SmemT {
    float x[FNB][HH];
    float h0[FNB][HH];
    float h1[FNB][HH];
};
__device__ __forceinline__ void lstm_layer_f32(
    const float (&s_in)[FNB][HH], float (&s_h)[FNB][HH],
    const float* __restrict__ Wxl, const float* __restrict__ Whl,
    float bi, float bf, float bg, float bo, float* cc, int m, int n0)
{
    float ai[8], af[8], ag[8], ao[8];
#pragma unroll
    for (int n = 0; n < 8; ++n) { ai[n] = bi; af[n] = bf; ag[n] = bg; ao[n] = bo; }
    const float* p = Wxl + m;
#pragma unroll 4
    for (int k = 0; k < HH; ++k) {
        float wi = p[0], wf = p[HH], wg = p[2 * HH], wo = p[3 * HH];
        p += GG;
#pragma unroll
        for (int n = 0; n < 8; ++n) {
            float xv = s_in[n0 + n][k];
            ai[n] = fmaf(xv, wi, ai[n]); af[n] = fmaf(xv, wf, af[n]);
            ag[n] = fmaf(xv, wg, ag[n]); ao[n] = fmaf(xv, wo, ao[n]);
        }
    }
    p = Whl + m;
#pragma unroll 4
    for (int k = 0; k < HH; ++k) {
        float wi = p[0], wf = p[HH], wg = p[2 * HH], wo = p[3 * HH];
        p += GG;
#pragma unroll
        for (int n = 0; n < 8; ++n) {
            float hv = s_h[n0 + n][k];
            ai[n] = fmaf(hv, wi, ai[n]); af[n] = fmaf(hv, wf, af[n]);
            ag[n] = fmaf(hv, wg, ag[n]); ao[n] = fmaf(hv, wo, ao[n]);
        }
    }
    __syncthreads();
#pragma unroll
    for (int n = 0; n < 8; ++n) {
        float iv = sig_(ai[n]), fv = sig_(af[n]), gv = tanh_(ag[n]), ov = sig_(ao[n]);
        float c = fmaf(fv, cc[n], iv * gv);
        cc[n] = c;
        s_h[n0 + n][m] = ov * tanh_(c);
    }
    __syncthreads();
}
__global__ __launch_bounds__(FNTH, 2) void node_lstm_fallback(
    const int* __restrict__ data, const float* __restrict__ embed,
    const float* __restrict__ Wx, const float* __restrict__ Wh,
    const float* __restrict__ bias, float* __restrict__ out, int vocab)
{
    __shared__ SmemT sm;
    const int tid = threadIdx.x;
    const int m = tid & (HH - 1);
    const int n0 = (tid >> 8) << 3;
    const int nodeBase = blockIdx.x * FNB;
    const float* Wx0 = Wx; const float* Wh0 = Wh;
    const float* Wx1 = Wx + HH * GG; const float* Wh1 = Wh + HH * GG;
    const float b0i = bias[m], b0f = bias[m + HH], b0g = bias[m + 2 * HH], b0o = bias[m + 3 * HH];
    const float b1i = bias[GG + m], b1f = bias[GG + m + HH], b1g = bias[GG + m + 2 * HH], b1o = bias[GG + m + 3 * HH];
    float c0[8], c1[8];
#pragma unroll
    for (int n = 0; n < 8; ++n) { c0[n] = 0.0f; c1[n] = 0.0f; }
    for (int idx = tid; idx < FNB * HH; idx += FNTH) {
        (&sm.h0[0][0])[idx] = 0.0f; (&sm.h1[0][0])[idx] = 0.0f;
    }
    __syncthreads();
    for (int t = 0; t < TT; ++t) {
        for (int idx = tid; idx < FNB * HH; idx += FNTH) {
            int n = idx >> 8, k = idx & (HH - 1);
            int row = data[(nodeBase + n) * TT + t];
            row = min(max(row, 0), vocab - 1);
            sm.x[n][k] = embed[(size_t)row * HH + k];
        }
        __syncthreads();
        lstm_layer_f32(sm.x, sm.h0, Wx0, Wh0, b0i, b0f, b0g, b0o, c0, m, n0);
        lstm_layer_f32(sm.h0, sm.h1, Wx1, Wh1, b1i, b1f, b1g, b1o, c1, m, n0);
    }
    for (int idx = tid; idx < FNB * HH; idx += FNTH) {
        int n = idx >> 8, k = idx & (HH - 1);
        out[(nodeBase + n) * HH + k] = sm.h1[n][k];
    }
}

// ---------------- launcher ----------------
extern "C" void kernel_launch(void* const* d_in, const int* in_sizes, int n_in,
                              void* d_out, int out_size, void* d_ws, size_t ws_size,
                              hipStream_t stream) {
    const int* data = (const int*)d_in[0];
    const float* embed = (const float*)d_in[1];
    const float* Wx = (const float*)d_in[2];
    const float* Wh = (const float*)d_in[3];
    const float* bias = (const float*)d_in[4];
    float* out = (float*)d_out;
    const int vocab = in_sizes[1] / HH;  // 30000

    if (ws_size < WS_NEED) {
        // not enough scratch for fp16 tables — safe fp32 path
        node_lstm_fallback<<<dim3(NN / FNB), dim3(FNTH), 0, stream>>>(
            data, embed, Wx, Wh, bias, out, vocab);
        return;
    }

    f16* emb_h = (f16*)d_ws;
    f16* Wp = (f16*)((char*)d_ws + EMB_BYTES);

    int n8 = in_sizes[1] / 8;  // 960000
    convert_embed<<<dim3((n8 + 255) / 256), dim3(256), 0, stream>>>(embed, emb_h, n8);
    pack_weights<<<dim3(131072 / 256), dim3(256), 0, stream>>>(Wx, Wh, Wp);

    lstm_mfma<<<dim3(NN / NB), dim3(NTH), 0, stream>>>(data, bias, emb_h, Wp, out, vocab);
}